// Round 1
// baseline (571.770 us; speedup 1.0000x reference)
//
#include <hip/hip_runtime.h>
#include <hip/hip_bf16.h>

#define VOCAB 32000
#define EMBED 1024
#define MTOK  4096   // B*T = 2*2048

typedef short bf16x8 __attribute__((ext_vector_type(8)));
typedef short short4v __attribute__((ext_vector_type(4)));
typedef short short8v __attribute__((ext_vector_type(8)));
typedef float f32x4 __attribute__((ext_vector_type(4)));

// f32 -> bf16 RNE (inputs are finite; no NaN handling needed)
__device__ __forceinline__ short f2bf(float f) {
    union { float f; unsigned u; } in;
    in.f = f;
    unsigned r = in.u + 0x7FFFu + ((in.u >> 16) & 1u);
    return (short)(r >> 16);
}

// async global->LDS, 16B per lane; LDS dest is wave-uniform base + lane*16
__device__ __forceinline__ void gload_lds16(const short* g, short* l) {
    __builtin_amdgcn_global_load_lds(
        (const __attribute__((address_space(1))) unsigned int*)g,
        (__attribute__((address_space(3))) unsigned int*)l,
        16, 0, 0);
}

// ---------------------------------------------------------------------------
// Kernel 1: emb[m][e] = bf16(We[e][tok[m]] + be[e]); A is [MTOK][EMBED] bf16
// one block per token row m; thread handles 4 consecutive e
// ---------------------------------------------------------------------------
__global__ void embed_gather(const int* __restrict__ tok,
                             const float* __restrict__ We,
                             const float* __restrict__ be,
                             short* __restrict__ A) {
    const int m = blockIdx.x;
    const int e = threadIdx.x * 4;
    const int t = tok[m];
    const float* w = We + (size_t)e * VOCAB + t;
    const float4 b4 = *(const float4*)(be + e);
    short4v o;
    o.x = f2bf(w[0] + b4.x);
    o.y = f2bf(w[(size_t)VOCAB] + b4.y);
    o.z = f2bf(w[(size_t)VOCAB * 2] + b4.z);
    o.w = f2bf(w[(size_t)VOCAB * 3] + b4.w);
    *(short4v*)(A + (size_t)m * EMBED + e) = o;
}

// ---------------------------------------------------------------------------
// Kernel 2: Wu f32 [VOCAB][EMBED] -> bf16, vectorized 8 elems/thread
// ---------------------------------------------------------------------------
__global__ void cvt_bf16(const float* __restrict__ W, short* __restrict__ O) {
    const size_t i = ((size_t)blockIdx.x * blockDim.x + threadIdx.x) * 8;
    const float4 a = *(const float4*)(W + i);
    const float4 b = *(const float4*)(W + i + 4);
    short8v o;
    o[0] = f2bf(a.x); o[1] = f2bf(a.y); o[2] = f2bf(a.z); o[3] = f2bf(a.w);
    o[4] = f2bf(b.x); o[5] = f2bf(b.y); o[6] = f2bf(b.z); o[7] = f2bf(b.w);
    *(short8v*)(O + i) = o;
}

// ---------------------------------------------------------------------------
// Kernel 3: C[m][v] = sum_k A[m][k]*B[v][k] + bu[v]
// m97-structure: 128x128 tile, BK=32, 4 waves (2x2), 16x16x32 bf16 MFMA,
// global_load_lds width=16, single-buffered LDS, 2 barriers / K-step.
// ---------------------------------------------------------------------------
__global__ __launch_bounds__(256) void gemm_bt128(
        const short* __restrict__ A,   // [MTOK][EMBED] bf16
        const short* __restrict__ B,   // [VOCAB][EMBED] bf16
        const float* __restrict__ bu,  // [VOCAB]
        float* __restrict__ C) {       // [MTOK][VOCAB] f32
    __shared__ __align__(16) short As[128 * 32];
    __shared__ __align__(16) short Bs[128 * 32];

    // XCD-bijective swizzle (8000 blocks, 8000%8==0): each XCD gets a
    // contiguous chunk; within a chunk, order is N-panel-major so the 32
    // M-tiles sharing one Wu panel hit the same XCD's L2.
    const int bid = blockIdx.x;
    const int cpx = 8000 >> 3;                 // 1000
    const int swz = (bid & 7) * cpx + (bid >> 3);
    const int ntile = swz / 32;                // 0..249
    const int mtile = swz & 31;                // 0..31
    const int m0 = mtile << 7;
    const int n0 = ntile << 7;

    const int tid = threadIdx.x;
    const int lane = tid & 63;
    const int w = tid >> 6;
    const int wr = w >> 1;                     // wave row (0..1)
    const int wc = w & 1;                      // wave col (0..1)

    // staging address map: idx = j*256 + tid covers [128 rows][4 x 16B]
    const int srow = tid >> 2;                 // 0..63
    const int scol = (tid & 3) << 3;           // short offset: 0,8,16,24

    const size_t baseA  = (size_t)(m0 + srow) * EMBED + scol;
    const size_t baseA2 = baseA + (size_t)64 * EMBED;
    const size_t baseB  = (size_t)(n0 + srow) * EMBED + scol;
    const size_t baseB2 = baseB + (size_t)64 * EMBED;

    short* ldsA0 = As + (w * 64) * 8;          // wave-uniform bases (x16B/lane)
    short* ldsA1 = As + (256 + w * 64) * 8;
    short* ldsB0 = Bs + (w * 64) * 8;
    short* ldsB1 = Bs + (256 + w * 64) * 8;

    f32x4 acc[4][4] = {};

    const int arow = wr * 64 + (lane & 15);
    const int brow = wc * 64 + (lane & 15);
    const int koff = (lane >> 4) << 3;         // k sub-block: 0,8,16,24

    for (int k0 = 0; k0 < EMBED; k0 += 32) {
        __syncthreads();                       // prev iter's ds_reads done
        gload_lds16(A + baseA  + k0, ldsA0);
        gload_lds16(A + baseA2 + k0, ldsA1);
        gload_lds16(B + baseB  + k0, ldsB0);
        gload_lds16(B + baseB2 + k0, ldsB1);
        __syncthreads();                       // compiler drains vmcnt(0)

        bf16x8 af[4], bfr[4];
#pragma unroll
        for (int i = 0; i < 4; ++i)
            af[i] = *(const bf16x8*)&As[(arow + i * 16) * 32 + koff];
#pragma unroll
        for (int i = 0; i < 4; ++i)
            bfr[i] = *(const bf16x8*)&Bs[(brow + i * 16) * 32 + koff];
#pragma unroll
        for (int i = 0; i < 4; ++i)
#pragma unroll
            for (int j = 0; j < 4; ++j)
                acc[i][j] = __builtin_amdgcn_mfma_f32_16x16x32_bf16(
                    af[i], bfr[j], acc[i][j], 0, 0, 0);
    }

    // epilogue: C/D layout col=lane&15, row=(lane>>4)*4+reg  (m89/m91)
    const int col0 = n0 + wc * 64;
    const int row0 = m0 + wr * 64 + ((lane >> 4) << 2);
#pragma unroll
    for (int j = 0; j < 4; ++j) {
        const int c = col0 + j * 16 + (lane & 15);
        const float bias = bu[c];
#pragma unroll
        for (int i = 0; i < 4; ++i) {
            const int r = row0 + i * 16;
            float* cp = C + (size_t)r * VOCAB + c;
#pragma unroll
            for (int q = 0; q < 4; ++q)
                cp[(size_t)q * VOCAB] = acc[i][j][q] + bias;
        }
    }
}

extern "C" void kernel_launch(void* const* d_in, const int* in_sizes, int n_in,
                              void* d_out, int out_size, void* d_ws, size_t ws_size,
                              hipStream_t stream) {
    const int*   tok = (const int*)d_in[0];
    const float* We  = (const float*)d_in[1];
    const float* be  = (const float*)d_in[2];
    const float* Wu  = (const float*)d_in[3];
    const float* bu  = (const float*)d_in[4];
    float* C = (float*)d_out;

    // workspace layout: Bb [VOCAB*EMBED] bf16 (65.5MB) then Ab [MTOK*EMBED]
    short* Bb = (short*)d_ws;
    short* Ab = Bb + (size_t)VOCAB * EMBED;

    // Wu -> bf16 : 32768000 elems / 8 per thread / 256 = 16000 blocks
    hipLaunchKernelGGL(cvt_bf16, dim3(16000), dim3(256), 0, stream, Wu, Bb);
    // emb gather : one block per token
    hipLaunchKernelGGL(embed_gather, dim3(MTOK), dim3(256), 0, stream,
                       tok, We, be, Ab);
    // GEMM: (4096/128) * (32000/128) = 32 * 250 = 8000 blocks
    hipLaunchKernelGGL(gemm_bt128, dim3(8000), dim3(256), 0, stream,
                       Ab, Bb, bu, C);
}

// Round 2
// 481.504 us; speedup vs baseline: 1.1875x; 1.1875x over previous
//
#include <hip/hip_runtime.h>
#include <hip/hip_bf16.h>

#define VOCAB 32000
#define EMBED 1024
#define MTOK  4096   // B*T = 2*2048

typedef short bf16x8 __attribute__((ext_vector_type(8)));
typedef short short4v __attribute__((ext_vector_type(4)));
typedef short short8v __attribute__((ext_vector_type(8)));
typedef float f32x4 __attribute__((ext_vector_type(4)));

// f32 -> bf16 RNE (inputs are finite; no NaN handling needed)
__device__ __forceinline__ short f2bf(float f) {
    union { float f; unsigned u; } in;
    in.f = f;
    unsigned r = in.u + 0x7FFFu + ((in.u >> 16) & 1u);
    return (short)(r >> 16);
}

// async global->LDS, 16B per lane; LDS dest is wave-uniform base + lane*16
__device__ __forceinline__ void gload_lds16(const short* g, short* l) {
    __builtin_amdgcn_global_load_lds(
        (const __attribute__((address_space(1))) unsigned int*)g,
        (__attribute__((address_space(3))) unsigned int*)l,
        16, 0, 0);
}

// ---------------------------------------------------------------------------
// Kernel 1: emb[m][e] = bf16(We[e][tok[m]] + be[e]); A is [MTOK][EMBED] bf16
// ---------------------------------------------------------------------------
__global__ void embed_gather(const int* __restrict__ tok,
                             const float* __restrict__ We,
                             const float* __restrict__ be,
                             short* __restrict__ A) {
    const int m = blockIdx.x;
    const int e = threadIdx.x * 4;
    const int t = tok[m];
    const float* w = We + (size_t)e * VOCAB + t;
    const float4 b4 = *(const float4*)(be + e);
    short4v o;
    o.x = f2bf(w[0] + b4.x);
    o.y = f2bf(w[(size_t)VOCAB] + b4.y);
    o.z = f2bf(w[(size_t)VOCAB * 2] + b4.z);
    o.w = f2bf(w[(size_t)VOCAB * 3] + b4.w);
    *(short4v*)(A + (size_t)m * EMBED + e) = o;
}

// ---------------------------------------------------------------------------
// Kernel 2: Wu f32 [VOCAB][EMBED] -> bf16
// ---------------------------------------------------------------------------
__global__ void cvt_bf16(const float* __restrict__ W, short* __restrict__ O) {
    const size_t i = ((size_t)blockIdx.x * blockDim.x + threadIdx.x) * 8;
    const float4 a = *(const float4*)(W + i);
    const float4 b = *(const float4*)(W + i + 4);
    short8v o;
    o[0] = f2bf(a.x); o[1] = f2bf(a.y); o[2] = f2bf(a.z); o[3] = f2bf(a.w);
    o[4] = f2bf(b.x); o[5] = f2bf(b.y); o[6] = f2bf(b.z); o[7] = f2bf(b.w);
    *(short8v*)(O + i) = o;
}

// ---------------------------------------------------------------------------
// Kernel 3: 256x256 tile, BK=64, 8 waves (2Mx4N), 8-phase schedule with
// counted vmcnt(4) at phases 4/8, st-XOR LDS swizzle, setprio around MFMA.
// LDS: A[2][256][64] + B[2][256][64] bf16 = 128 KiB (dynamic).
// ---------------------------------------------------------------------------
#define AOFF0 0
#define AOFF1 16384
#define BOFF0 32768
#define BOFF1 49152

#define BAR  __builtin_amdgcn_s_barrier()
#define PRIO1 __builtin_amdgcn_s_setprio(1)
#define PRIO0 __builtin_amdgcn_s_setprio(0)
#define VMW4 asm volatile("s_waitcnt vmcnt(4)" ::: "memory")

// stage one half-tile [128][64] of matrix at g (tile-row base) into lds+boff.
// linear LDS dest (gload_lds requirement); source slot pre-swizzled so that
// LDS slot s of row r holds global slot s^(r&7)  (involution, both-sides rule)
#define STAGE(g, boff, h, kofs) do {                                          \
    const short* _s = (g) + (size_t)(128*(h) + 8*w + srowL) * EMBED           \
                      + (kofs) + 8*sslot;                                     \
    gload_lds16(_s, lds + (boff) + (128*(h) + 8*w)*64);                       \
    gload_lds16(_s + (size_t)64*EMBED,                                        \
                lds + (boff) + (128*(h) + 64 + 8*w)*64);                      \
} while (0)

// read A fragments for row-half rh (4 rowfrags x 2 ksteps)
#define LDA_H(rh, boff) do {                                                  \
    _Pragma("unroll")                                                         \
    for (int j = 0; j < 4; ++j) {                                             \
        const int r_ = rA + ((rh)*4 + j)*16;                                  \
        _Pragma("unroll")                                                     \
        for (int ks = 0; ks < 2; ++ks)                                        \
            af[j][ks] = *(const bf16x8*)(lds + (boff) + r_*64                 \
                                         + 8*((4*ks + ghi) ^ r7));            \
    }                                                                         \
} while (0)

// read B fragments for col-half ch (2 colfrags x 2 ksteps)
#define LDB_H(ch, boff) do {                                                  \
    _Pragma("unroll")                                                         \
    for (int j = 0; j < 2; ++j) {                                             \
        const int r_ = rB + ((ch)*2 + j)*16;                                  \
        _Pragma("unroll")                                                     \
        for (int ks = 0; ks < 2; ++ks)                                        \
            bf[(ch)*2 + j][ks] = *(const bf16x8*)(lds + (boff) + r_*64        \
                                                  + 8*((4*ks + ghi) ^ r7));   \
    }                                                                         \
} while (0)

#define MFMA16(rh, ch) do {                                                   \
    PRIO1;                                                                    \
    _Pragma("unroll")                                                         \
    for (int j = 0; j < 4; ++j)                                               \
        _Pragma("unroll")                                                     \
        for (int c = 0; c < 2; ++c)                                           \
            _Pragma("unroll")                                                 \
            for (int ks = 0; ks < 2; ++ks)                                    \
                acc[(rh)*4 + j][(ch)*2 + c] =                                 \
                    __builtin_amdgcn_mfma_f32_16x16x32_bf16(                  \
                        af[j][ks], bf[(ch)*2 + c][ks],                        \
                        acc[(rh)*4 + j][(ch)*2 + c], 0, 0, 0);                \
    PRIO0;                                                                    \
} while (0)

__global__ __launch_bounds__(512, 2) void gemm256(
        const short* __restrict__ A,   // [MTOK][EMBED] bf16
        const short* __restrict__ B,   // [VOCAB][EMBED] bf16
        const float* __restrict__ bu,  // [VOCAB]
        float* __restrict__ C) {       // [MTOK][VOCAB] f32
    extern __shared__ short lds[];

    // XCD-bijective swizzle: 2000 blocks = 8 x 250; n-major within each XCD
    // chunk so the 16 M-blocks sharing a Wu panel are temporally close.
    const int bid = blockIdx.x;
    const int T = (bid & 7) * 250 + (bid >> 3);
    const int ntile = T >> 4;            // 0..124
    const int mtile = T & 15;            // 0..15
    const int m0 = mtile << 8;
    const int n0 = ntile << 8;

    const int tid  = threadIdx.x;
    const int lane = tid & 63;
    const int w    = tid >> 6;           // wave 0..7
    const int wr   = w >> 2;             // 0..1 (M)
    const int wc   = w & 3;              // 0..3 (N)

    // staging lane decomposition: lane = 8*srowL + (lane&7)
    const int srowL = lane >> 3;                  // row within 8-group
    const int sslot = (lane & 7) ^ srowL;         // pre-swizzled source slot

    // read-side per-lane constants
    const int rA  = wr * 128 + (lane & 15);
    const int rB  = wc * 64  + (lane & 15);
    const int ghi = lane >> 4;                    // k subgroup 0..3
    const int r7  = lane & 7;                     // row&7 for all frag rows

    const short* Ag = A + (size_t)m0 * EMBED;
    const short* Bg = B + (size_t)n0 * EMBED;

    f32x4 acc[8][4] = {};
    bf16x8 af[4][2], bf[4][2];

    // prologue: tile0 (buf0) fully + tile1's B halves (buf1)
    STAGE(Bg, BOFF0, 0, 0);  STAGE(Bg, BOFF0, 1, 0);
    STAGE(Ag, AOFF0, 0, 0);  STAGE(Ag, AOFF0, 1, 0);
    STAGE(Bg, BOFF1, 0, 64); STAGE(Bg, BOFF1, 1, 64);
    VMW4;                         // tile0 landed; tile1-B (4) in flight
    BAR;

#pragma unroll 1
    for (int i = 0; i < 8; ++i) {
        const int k1 = ((2*i + 1) & 15) * 64;   // tile t1 = 2i+1
        const int k2 = ((2*i + 2) & 15) * 64;   // tile t0+2 (wraps harmlessly)
        const int k3 = ((2*i + 3) & 15) * 64;   // tile t1+2

        // P1: consume buf0 quad(0,0); stage A-h0(t1)->buf1
        LDA_H(0, AOFF0); LDB_H(0, BOFF0);
        STAGE(Ag, AOFF1, 0, k1);
        BAR; MFMA16(0, 0); BAR;
        // P2: quad(0,1); stage A-h1(t1)->buf1
        LDB_H(1, BOFF0);
        STAGE(Ag, AOFF1, 1, k1);
        BAR; MFMA16(0, 1); BAR;
        // P3: quad(1,0); stage B-h0(t0+2)->buf0 (B of buf0 dead after P2)
        LDA_H(1, AOFF0);
        STAGE(Bg, BOFF0, 0, k2);
        BAR; MFMA16(1, 0); BAR;
        // P4: quad(1,1); stage B-h1(t0+2)->buf0; counted wait for tile t1
        STAGE(Bg, BOFF0, 1, k2);
        BAR; MFMA16(1, 1);
        VMW4;                     // t1 all landed; B(t0+2) (4) in flight
        BAR;
        // P5: consume buf1 quad(0,0); stage A-h0(t0+2)->buf0 (A dead after P3)
        LDA_H(0, AOFF1); LDB_H(0, BOFF1);
        STAGE(Ag, AOFF0, 0, k2);
        BAR; MFMA16(0, 0); BAR;
        // P6: quad(0,1); stage A-h1(t0+2)->buf0
        LDB_H(1, BOFF1);
        STAGE(Ag, AOFF0, 1, k2);
        BAR; MFMA16(0, 1); BAR;
        // P7: quad(1,0); stage B-h0(t1+2)->buf1
        LDA_H(1, AOFF1);
        STAGE(Bg, BOFF1, 0, k3);
        BAR; MFMA16(1, 0); BAR;
        // P8: quad(1,1); stage B-h1(t1+2)->buf1; counted wait for tile t0+2
        STAGE(Bg, BOFF1, 1, k3);
        BAR; MFMA16(1, 1);
        VMW4;                     // t0+2 all landed; B(t1+2) (4) in flight
        BAR;
    }

    // epilogue: C/D layout col=lane&15, row=(lane>>4)*4+q
    const int erow0 = m0 + wr * 128 + ((lane >> 4) << 2);
    const int ecol0 = n0 + wc * 64 + (lane & 15);
#pragma unroll
    for (int cf = 0; cf < 4; ++cf) {
        const int c = ecol0 + cf * 16;
        const float bias = bu[c];
#pragma unroll
        for (int rf = 0; rf < 8; ++rf) {
            float* cp = C + (size_t)(erow0 + rf * 16) * VOCAB + c;
#pragma unroll
            for (int q = 0; q < 4; ++q)
                cp[(size_t)q * VOCAB] = acc[rf][cf][q] + bias;
        }
    }
}

extern "C" void kernel_launch(void* const* d_in, const int* in_sizes, int n_in,
                              void* d_out, int out_size, void* d_ws, size_t ws_size,
                              hipStream_t stream) {
    const int*   tok = (const int*)d_in[0];
    const float* We  = (const float*)d_in[1];
    const float* be  = (const float*)d_in[2];
    const float* Wu  = (const float*)d_in[3];
    const float* bu  = (const float*)d_in[4];
    float* C = (float*)d_out;

    short* Bb = (short*)d_ws;                        // [VOCAB][EMBED] bf16
    short* Ab = Bb + (size_t)VOCAB * EMBED;          // [MTOK][EMBED] bf16

    (void)hipFuncSetAttribute((const void*)gemm256,
                              hipFuncAttributeMaxDynamicSharedMemorySize,
                              131072);

    hipLaunchKernelGGL(cvt_bf16, dim3(16000), dim3(256), 0, stream, Wu, Bb);
    hipLaunchKernelGGL(embed_gather, dim3(MTOK), dim3(256), 0, stream,
                       tok, We, be, Ab);
    // GEMM: (4096/256) * (32000/256) = 16 * 125 = 2000 blocks
    hipLaunchKernelGGL(gemm256, dim3(2000), dim3(512), 131072, stream,
                       Ab, Bb, bu, C);
}